// Round 13
// baseline (18736.942 us; speedup 1.0000x reference)
//
#include <hip/hip_runtime.h>
#include <cstdint>

// Reference semantics (validated R8, absmax=0.0 — DO NOT change arithmetic):
//  - selection on RAW f32 coords, distance = fma(dz,dz, fma(dx,dx, dy*dy))
//    with dx/dy/dz plain f32 subs; min/argmax exact, first-index tie-break;
//  - output coords bf16-RNE-rounded, batch = float b.
//
// R13: Morton-bucketed FPS with provably-exact skipping.
//  Phase A: per cloud, counting-sort points by 8^3 Morton cell into ws
//           (SoA xs/ys/zs + orig idx), bbox per 32-point chunk.
//  Phase B: thread t owns chunk t. Per iteration: lb = minDist^2(bbox,c)*0.999;
//           if lb >= bv_t the whole chunk provably cannot change (d_comp >=
//           lb*(1+eps) >= bv >= mind_i, margin 1e-3 >> 1e-6 rounding) ->
//           skip the update, keep cached (bv,bg). Values of (mind_i, g_i) are
//           ownership- and order-invariant, so selection stays bitwise exact.
#pragma clang fp contract(off)

#define B_ 16
#define N_ 16384
#define K_ 4096

#define TA_ 1024
#define PA_ (N_ / TA_)          // 16 pts/thread in sort kernel
#define NCELL_ 512              // 8^3 Morton cells

#define TB_ 512
#define CH_ 32                  // points per chunk (one chunk per thread)
#define NWB_ (TB_ / 64)         // 8 waves

// ws layout per cloud, in 4-byte units
#define WS_XS 0
#define WS_YS N_
#define WS_ZS (2 * N_)
#define WS_MD (3 * N_)
#define WS_ID (4 * N_)
#define WS_BB (5 * N_)
#define WS_CLOUD (5 * N_ + TB_ * 6)
#define WS_NEED ((size_t)B_ * WS_CLOUD * 4)

__device__ __forceinline__ float bfr(float f) {
  union { float f; uint32_t i; } c; c.f = f;
  c.i = (c.i + 0x7FFFu + ((c.i >> 16) & 1u)) & 0xFFFF0000u;
  return c.f;
}

__device__ __forceinline__ float dist_v1(float px, float py, float pz,
                                         float cx, float cy, float cz) {
  const float dx = px - cx;
  const float dy = py - cy;
  const float dz = pz - cz;
  return __builtin_fmaf(dz, dz, __builtin_fmaf(dx, dx, dy * dy));
}

__device__ __forceinline__ int cell1(float v) {
  int k = (int)(v + 4.0f);
  return k < 0 ? 0 : (k > 7 ? 7 : k);
}
__device__ __forceinline__ int expand3(int b) {
  return (b & 1) | ((b & 2) << 2) | ((b & 4) << 4);   // bits -> 0,3,6
}
__device__ __forceinline__ int mkey(float vx, float vy, float vz) {
  return (expand3(cell1(vx)) << 2) | (expand3(cell1(vy)) << 1) | expand3(cell1(vz));
}

// ---------------- Phase A: Morton counting sort + chunk bboxes ----------------
__global__ __launch_bounds__(TA_) void fps_sort_kernel(
    const float* __restrict__ x, float* __restrict__ ws)
{
  const int b = blockIdx.x, t = threadIdx.x;
  __shared__ int hist[NCELL_];
  __shared__ int scan[NCELL_];
  const float* xb = x + (size_t)b * (N_ * 3);
  float* wsc = ws + (size_t)b * WS_CLOUD;
  int* oid = (int*)(wsc + WS_ID);

  for (int i = t; i < NCELL_; i += TA_) hist[i] = 0;
  __syncthreads();

  for (int s = 0; s < PA_; ++s) {
    const int g = s * TA_ + t;
    atomicAdd(&hist[mkey(xb[3 * g], xb[3 * g + 1], xb[3 * g + 2])], 1);
  }
  __syncthreads();

  // inclusive scan (Hillis-Steele) of hist -> scan
  if (t < NCELL_) scan[t] = hist[t];
  __syncthreads();
  for (int d = 1; d < NCELL_; d <<= 1) {
    int v = 0;
    if (t < NCELL_) { v = scan[t]; if (t >= d) v += scan[t - d]; }
    __syncthreads();
    if (t < NCELL_) scan[t] = v;
    __syncthreads();
  }
  if (t < NCELL_) hist[t] = (t == 0) ? 0 : scan[t - 1];  // exclusive starts = cursors
  __syncthreads();

  for (int s = 0; s < PA_; ++s) {
    const int g = s * TA_ + t;
    const float vx = xb[3 * g], vy = xb[3 * g + 1], vz = xb[3 * g + 2];
    const int pos = atomicAdd(&hist[mkey(vx, vy, vz)], 1);
    wsc[WS_XS + pos] = vx;
    wsc[WS_YS + pos] = vy;
    wsc[WS_ZS + pos] = vz;
    oid[pos] = g;
  }
  __threadfence();
  __syncthreads();

  if (t < TB_) {
    const int base = t * CH_;
    float xl = 1e30f, xh = -1e30f, yl = 1e30f, yh = -1e30f, zl = 1e30f, zh = -1e30f;
    for (int i = 0; i < CH_; ++i) {
      const float vx = wsc[WS_XS + base + i];
      const float vy = wsc[WS_YS + base + i];
      const float vz = wsc[WS_ZS + base + i];
      xl = fminf(xl, vx); xh = fmaxf(xh, vx);
      yl = fminf(yl, vy); yh = fmaxf(yh, vy);
      zl = fminf(zl, vz); zh = fmaxf(zh, vz);
    }
    float* bb = wsc + WS_BB + t * 6;
    bb[0] = xl; bb[1] = xh; bb[2] = yl; bb[3] = yh; bb[4] = zl; bb[5] = zh;
  }
}

// ---------------- Phase B: FPS with exact bucket skipping ----------------
#define TRK(mv, ov) { if ((mv) > bv || ((mv) == bv && (ov) < bg)) { bv = (mv); bg = (ov); } }

__global__ __launch_bounds__(TB_) void fps_main_kernel(
    const float* __restrict__ x, float* __restrict__ ws, float* __restrict__ out)
{
#pragma clang fp contract(off)
  const int b = blockIdx.x, t = threadIdx.x, lane = t & 63, wave = t >> 6;
  __shared__ float s_v[2][NWB_];
  __shared__ int   s_g[2][NWB_];

  const float* xb = x + (size_t)b * (N_ * 3);
  float* wsc = ws + (size_t)b * WS_CLOUD;
  const float* xs = wsc + WS_XS;
  const float* ysv = wsc + WS_YS;
  const float* zsv = wsc + WS_ZS;
  float* md = wsc + WS_MD;
  const int* oid = (const int*)(wsc + WS_ID);

  float* out_x = out;
  float* out_b = out + (size_t)B_ * K_ * 3;
  { const float bb = (float)b; for (int i = t; i < K_; i += TB_) out_b[b * K_ + i] = bb; }

  const float* bbp = wsc + WS_BB + t * 6;
  const float bxl = bbp[0], bxh = bbp[1], byl = bbp[2], byh = bbp[3], bzl = bbp[4], bzh = bbp[5];
  const int base = t * CH_;

  // ---- iteration 0: seed = original point 0 ----
  float cx = xb[0], cy = xb[1], cz = xb[2];
  if (t == 0) {
    const uint64_t o = ((uint64_t)b * K_) * 3;
    out_x[o + 0] = bfr(cx); out_x[o + 1] = bfr(cy); out_x[o + 2] = bfr(cz);
  }

  float bv = -1e38f; int bg = 0x7fffffff;
  for (int i = 0; i < CH_; i += 4) {
    const float4 px = *(const float4*)(xs + base + i);
    const float4 py = *(const float4*)(ysv + base + i);
    const float4 pz = *(const float4*)(zsv + base + i);
    const int4   o4 = *(const int4*)(oid + base + i);
    float4 m4;
    m4.x = dist_v1(px.x, py.x, pz.x, cx, cy, cz); TRK(m4.x, o4.x);
    m4.y = dist_v1(px.y, py.y, pz.y, cx, cy, cz); TRK(m4.y, o4.y);
    m4.z = dist_v1(px.z, py.z, pz.z, cx, cy, cz); TRK(m4.z, o4.z);
    m4.w = dist_v1(px.w, py.w, pz.w, cx, cy, cz); TRK(m4.w, o4.w);
    *(float4*)(md + base + i) = m4;
  }
  {
    float rv = bv; int rg = bg;
#pragma unroll
    for (int m = 32; m >= 1; m >>= 1) {
      const float ov = __shfl_xor(rv, m, 64);
      const int   og = __shfl_xor(rg, m, 64);
      if (ov > rv || (ov == rv && og < rg)) { rv = ov; rg = og; }
    }
    if (lane == 0) { s_v[0][wave] = rv; s_g[0][wave] = rg; }
  }
  __syncthreads();

  // ---- iterations 1..K-1 ----
  for (int j = 1; j < K_; ++j) {
    const int rp = (j - 1) & 1;
    const int wp = j & 1;

    // block argmax finalize: butterfly over the NWB_ per-wave slots
    float v = s_v[rp][lane & (NWB_ - 1)];
    int   g = s_g[rp][lane & (NWB_ - 1)];
#pragma unroll
    for (int m = NWB_ / 2; m >= 1; m >>= 1) {
      const float ov = __shfl_xor(v, m, 64);
      const int   og = __shfl_xor(g, m, 64);
      if (ov > v || (ov == v && og < g)) { v = ov; g = og; }
    }

    const int gu = __builtin_amdgcn_readfirstlane(g);
    cx = xb[3 * gu + 0];
    cy = xb[3 * gu + 1];
    cz = xb[3 * gu + 2];
    if (t == 0) {
      const uint64_t o = ((uint64_t)b * K_ + j) * 3;
      out_x[o + 0] = bfr(cx); out_x[o + 1] = bfr(cy); out_x[o + 2] = bfr(cz);
    }

    // conservative lower bound of chunk distance to c
    const float dxm = fmaxf(fmaxf(bxl - cx, cx - bxh), 0.0f);
    const float dym = fmaxf(fmaxf(byl - cy, cy - byh), 0.0f);
    const float dzm = fmaxf(fmaxf(bzl - cz, cz - bzh), 0.0f);
    const float lb  = (dxm * dxm + dym * dym + dzm * dzm) * 0.999f;

    if (lb < bv) {   // chunk may change -> exact update
      bv = -1e38f; bg = 0x7fffffff;
      for (int i = 0; i < CH_; i += 4) {
        const float4 px = *(const float4*)(xs + base + i);
        const float4 py = *(const float4*)(ysv + base + i);
        const float4 pz = *(const float4*)(zsv + base + i);
        const int4   o4 = *(const int4*)(oid + base + i);
        float4 m4 = *(float4*)(md + base + i);
        float d;
        d = dist_v1(px.x, py.x, pz.x, cx, cy, cz); m4.x = fminf(m4.x, d); TRK(m4.x, o4.x);
        d = dist_v1(px.y, py.y, pz.y, cx, cy, cz); m4.y = fminf(m4.y, d); TRK(m4.y, o4.y);
        d = dist_v1(px.z, py.z, pz.z, cx, cy, cz); m4.z = fminf(m4.z, d); TRK(m4.z, o4.z);
        d = dist_v1(px.w, py.w, pz.w, cx, cy, cz); m4.w = fminf(m4.w, d); TRK(m4.w, o4.w);
        *(float4*)(md + base + i) = m4;
      }
    }

    float rv = bv; int rg = bg;
#pragma unroll
    for (int m = 32; m >= 1; m >>= 1) {
      const float ov = __shfl_xor(rv, m, 64);
      const int   og = __shfl_xor(rg, m, 64);
      if (ov > rv || (ov == rv && og < rg)) { rv = ov; rg = og; }
    }
    if (lane == 0) { s_v[wp][wave] = rv; s_g[wp][wave] = rg; }
    __syncthreads();
  }
}

// ---------------- Fallback (R11): self-contained, no ws ----------------
#define FTH_ 512
#define FPTS_ 32
#define FNW_ (FTH_ / 64)
#define PTS_LIST(X) \
  X(0) X(1) X(2) X(3) X(4) X(5) X(6) X(7) \
  X(8) X(9) X(10) X(11) X(12) X(13) X(14) X(15) \
  X(16) X(17) X(18) X(19) X(20) X(21) X(22) X(23) \
  X(24) X(25) X(26) X(27) X(28) X(29) X(30) X(31)

__global__ __attribute__((amdgpu_flat_work_group_size(FTH_, FTH_),
                          amdgpu_waves_per_eu(1, 2)))
void fps_fallback_kernel(const float* __restrict__ x, float* __restrict__ out)
{
#pragma clang fp contract(off)
  const int b = blockIdx.x, t = threadIdx.x, lane = t & 63, wave = t >> 6;
  __shared__ float s_v[2][FNW_];
  __shared__ int   s_g[2][FNW_];
  const float* xb  = x + (size_t)b * (N_ * 3);
  float* out_x     = out;
  float* out_batch = out + (size_t)B_ * K_ * 3;
  { const float bb = (float)b; for (int i = t; i < K_; i += FTH_) out_batch[b * K_ + i] = bb; }
#define DECLP(i) float px##i, py##i, pz##i, m##i;
  PTS_LIST(DECLP)
#undef DECLP
#define LOADP(i) { const float* p_ = xb + 3 * ((i) * FTH_ + t); \
                   px##i = p_[0]; py##i = p_[1]; pz##i = p_[2]; m##i = __builtin_inff(); }
  PTS_LIST(LOADP)
#undef LOADP
#define UPD(i) { const float d_ = dist_v1(px##i, py##i, pz##i, cx, cy, cz);     \
                 m##i = fminf(m##i, d_);                                        \
                 if (m##i > bv) { bv = m##i; bs = (i); } }
  float cx = xb[0], cy = xb[1], cz = xb[2];
  if (t == 0) {
    const uint64_t o = ((uint64_t)b * K_) * 3;
    out_x[o + 0] = bfr(cx); out_x[o + 1] = bfr(cy); out_x[o + 2] = bfr(cz);
  }
  float bv = -1.0f; int bs = 0;
  PTS_LIST(UPD)
  int bg = bs * FTH_ + t;
#pragma unroll
  for (int m = 32; m >= 1; m >>= 1) {
    const float ov = __shfl_xor(bv, m, 64);
    const int   og = __shfl_xor(bg, m, 64);
    if (ov > bv || (ov == bv && og < bg)) { bv = ov; bg = og; }
  }
  if (lane == 0) { s_v[0][wave] = bv; s_g[0][wave] = bg; }
  __syncthreads();
  for (int j = 1; j < K_; ++j) {
    const int rp = (j - 1) & 1, wp = j & 1;
    float v = s_v[rp][0]; int g = s_g[rp][0];
#pragma unroll
    for (int w = 1; w < FNW_; ++w) {
      const float ov = s_v[rp][w]; const int og = s_g[rp][w];
      if (ov > v || (ov == v && og < g)) { v = ov; g = og; }
    }
    const int gu = __builtin_amdgcn_readfirstlane(g);
    cx = xb[3 * gu + 0]; cy = xb[3 * gu + 1]; cz = xb[3 * gu + 2];
    if (t == 0) {
      const uint64_t o = ((uint64_t)b * K_ + j) * 3;
      out_x[o + 0] = bfr(cx); out_x[o + 1] = bfr(cy); out_x[o + 2] = bfr(cz);
    }
    bv = -1.0f; bs = 0;
    PTS_LIST(UPD)
    bg = bs * FTH_ + t;
#pragma unroll
    for (int m = 32; m >= 1; m >>= 1) {
      const float ov = __shfl_xor(bv, m, 64);
      const int   og = __shfl_xor(bg, m, 64);
      if (ov > bv || (ov == bv && og < bg)) { bv = ov; bg = og; }
    }
    if (lane == 0) { s_v[wp][wave] = bv; s_g[wp][wave] = bg; }
    __syncthreads();
  }
#undef UPD
}

extern "C" void kernel_launch(void* const* d_in, const int* in_sizes, int n_in,
                              void* d_out, int out_size, void* d_ws, size_t ws_size,
                              hipStream_t stream) {
  const float* x = (const float*)d_in[0];
  float* out     = (float*)d_out;
  (void)in_sizes; (void)n_in; (void)out_size;
  if (ws_size >= WS_NEED) {
    float* ws = (float*)d_ws;
    hipLaunchKernelGGL(fps_sort_kernel, dim3(B_), dim3(TA_), 0, stream, x, ws);
    hipLaunchKernelGGL(fps_main_kernel, dim3(B_), dim3(TB_), 0, stream, x, ws, out);
  } else {
    hipLaunchKernelGGL(fps_fallback_kernel, dim3(B_), dim3(FTH_), 0, stream, x, out);
  }
}

// Round 14
// 14451.259 us; speedup vs baseline: 1.2966x; 1.2966x over previous
//
#include <hip/hip_runtime.h>
#include <cstdint>

// Reference semantics (validated R8, absmax=0.0 — DO NOT change arithmetic):
//  - selection on RAW f32 coords, distance = fma(dz,dz, fma(dx,dx, dy*dy))
//    with dx/dy/dz plain f32 subs; min/argmax exact over (value, orig-index)
//    with first-index tie-break (lex (max v, min g) — commutative reduce);
//  - output coords bf16-RNE-rounded, batch = float b.
//
// R14 = R11 (register-resident) + R13 (Morton sort + provably-exact skip)
//  - per-thread: 32 sorted points + mind + orig ids as NAMED SCALARS;
//  - skip: lb = minDist^2(bbox,c)*0.999 >= bv  ==> chunk provably unchanged
//    (computed d >= true_d*(1-3eps) >= bbox_dist^2*(1-3eps) > lb >= bv >=
//     every mind_i in chunk; margin 1e-3 >> 4e-7 rounding);
//  - winner coords CARRIED through the reduction (no memory on serial path).
#pragma clang fp contract(off)

#define B_ 16
#define N_ 16384
#define K_ 4096

#define TA_ 1024
#define PA_ (N_ / TA_)
#define NCELL_ 512              // 8^3 Morton cells

#define TB_ 512
#define CH_ 32                  // points per chunk = per thread
#define NWB_ (TB_ / 64)         // 8 waves

// ws layout per cloud (4-byte units): xs, ys, zs, id, bbox[TB_*6]
#define WS_XS 0
#define WS_YS N_
#define WS_ZS (2 * N_)
#define WS_ID (3 * N_)
#define WS_BB (4 * N_)
#define WS_CLOUD (4 * N_ + TB_ * 6)
#define WS_NEED ((size_t)B_ * WS_CLOUD * 4)

#define PTS_LIST(X) \
  X(0) X(1) X(2) X(3) X(4) X(5) X(6) X(7) \
  X(8) X(9) X(10) X(11) X(12) X(13) X(14) X(15) \
  X(16) X(17) X(18) X(19) X(20) X(21) X(22) X(23) \
  X(24) X(25) X(26) X(27) X(28) X(29) X(30) X(31)

__device__ __forceinline__ float bfr(float f) {
  union { float f; uint32_t i; } c; c.f = f;
  c.i = (c.i + 0x7FFFu + ((c.i >> 16) & 1u)) & 0xFFFF0000u;
  return c.f;
}

__device__ __forceinline__ float dist_v1(float px, float py, float pz,
                                         float cx, float cy, float cz) {
  const float dx = px - cx;
  const float dy = py - cy;
  const float dz = pz - cz;
  return __builtin_fmaf(dz, dz, __builtin_fmaf(dx, dx, dy * dy));
}

__device__ __forceinline__ int cell1(float v) {
  int k = (int)(v + 4.0f);
  return k < 0 ? 0 : (k > 7 ? 7 : k);
}
__device__ __forceinline__ int expand3(int b) {
  return (b & 1) | ((b & 2) << 2) | ((b & 4) << 4);
}
__device__ __forceinline__ int mkey(float vx, float vy, float vz) {
  return (expand3(cell1(vx)) << 2) | (expand3(cell1(vy)) << 1) | expand3(cell1(vz));
}

// ---------------- Phase A: Morton counting sort + chunk bboxes ----------------
__global__ __launch_bounds__(TA_) void fps_sort_kernel(
    const float* __restrict__ x, float* __restrict__ ws)
{
  const int b = blockIdx.x, t = threadIdx.x;
  __shared__ int hist[NCELL_];
  __shared__ int scan[NCELL_];
  const float* xb = x + (size_t)b * (N_ * 3);
  float* wsc = ws + (size_t)b * WS_CLOUD;
  int* oid = (int*)(wsc + WS_ID);

  for (int i = t; i < NCELL_; i += TA_) hist[i] = 0;
  __syncthreads();
  for (int s = 0; s < PA_; ++s) {
    const int g = s * TA_ + t;
    atomicAdd(&hist[mkey(xb[3 * g], xb[3 * g + 1], xb[3 * g + 2])], 1);
  }
  __syncthreads();
  if (t < NCELL_) scan[t] = hist[t];
  __syncthreads();
  for (int d = 1; d < NCELL_; d <<= 1) {
    int v = 0;
    if (t < NCELL_) { v = scan[t]; if (t >= d) v += scan[t - d]; }
    __syncthreads();
    if (t < NCELL_) scan[t] = v;
    __syncthreads();
  }
  if (t < NCELL_) hist[t] = (t == 0) ? 0 : scan[t - 1];
  __syncthreads();
  for (int s = 0; s < PA_; ++s) {
    const int g = s * TA_ + t;
    const float vx = xb[3 * g], vy = xb[3 * g + 1], vz = xb[3 * g + 2];
    const int pos = atomicAdd(&hist[mkey(vx, vy, vz)], 1);
    wsc[WS_XS + pos] = vx;
    wsc[WS_YS + pos] = vy;
    wsc[WS_ZS + pos] = vz;
    oid[pos] = g;
  }
  __threadfence();
  __syncthreads();
  if (t < TB_) {
    const int base = t * CH_;
    float xl = 1e30f, xh = -1e30f, yl = 1e30f, yh = -1e30f, zl = 1e30f, zh = -1e30f;
    for (int i = 0; i < CH_; ++i) {
      const float vx = wsc[WS_XS + base + i];
      const float vy = wsc[WS_YS + base + i];
      const float vz = wsc[WS_ZS + base + i];
      xl = fminf(xl, vx); xh = fmaxf(xh, vx);
      yl = fminf(yl, vy); yh = fmaxf(yh, vy);
      zl = fminf(zl, vz); zh = fmaxf(zh, vz);
    }
    float* bb = wsc + WS_BB + t * 6;
    bb[0] = xl; bb[1] = xh; bb[2] = yl; bb[3] = yh; bb[4] = zl; bb[5] = zh;
  }
}

// ---------------- Phase B: register-resident FPS with exact skipping ----------
__global__ __attribute__((amdgpu_flat_work_group_size(TB_, TB_),
                          amdgpu_waves_per_eu(1, 2)))
void fps_main_kernel(const float* __restrict__ x, const float* __restrict__ ws,
                     float* __restrict__ out)
{
#pragma clang fp contract(off)
  const int b = blockIdx.x, t = threadIdx.x, lane = t & 63, wave = t >> 6;
  __shared__ float s_v[2][NWB_], s_x[2][NWB_], s_y[2][NWB_], s_z[2][NWB_];
  __shared__ int   s_g[2][NWB_];

  const float* xb  = x + (size_t)b * (N_ * 3);
  const float* wsc = ws + (size_t)b * WS_CLOUD;
  const float* xs  = wsc + WS_XS;
  const float* ysv = wsc + WS_YS;
  const float* zsv = wsc + WS_ZS;
  const int*   oid = (const int*)(wsc + WS_ID);

  float* out_x = out;
  float* out_b = out + (size_t)B_ * K_ * 3;
  { const float bb = (float)b; for (int i = t; i < K_; i += TB_) out_b[b * K_ + i] = bb; }

  // chunk bbox (registers)
  const float* bbp = wsc + WS_BB + t * 6;
  const float bxl = bbp[0], bxh = bbp[1], byl = bbp[2], byh = bbp[3], bzl = bbp[4], bzh = bbp[5];
  const int base = t * CH_;

  // named per-point scalars: coords + mind + orig index
#define DECLP(i) float px##i, py##i, pz##i, m##i; int od##i;
  PTS_LIST(DECLP)
#undef DECLP
#define LOADP(i) { px##i = xs[base + (i)]; py##i = ysv[base + (i)]; \
                   pz##i = zsv[base + (i)]; od##i = oid[base + (i)]; }
  PTS_LIST(LOADP)
#undef LOADP

  // cached chunk-best (value, orig idx, coords of that point)
  float bv, bcx, bcy, bcz; int bg;

#define TRKC(mv, ov, qx, qy, qz) \
  if ((mv) > bv || ((mv) == bv && (ov) < bg)) { \
    bv = (mv); bg = (ov); bcx = (qx); bcy = (qy); bcz = (qz); }

  // ---- iteration 0: seed = original point 0 ----
  float wcx = xb[0], wcy = xb[1], wcz = xb[2];
  if (t == 0) {
    const uint64_t o = ((uint64_t)b * K_) * 3;
    out_x[o + 0] = bfr(wcx); out_x[o + 1] = bfr(wcy); out_x[o + 2] = bfr(wcz);
  }

  bv = -1e38f; bg = 0x7fffffff;
#define INITP(i) { const float d_ = dist_v1(px##i, py##i, pz##i, wcx, wcy, wcz); \
                   m##i = d_; TRKC(m##i, od##i, px##i, py##i, pz##i) }
  PTS_LIST(INITP)
#undef INITP

  // wave reduce of cached 5-tuple -> LDS slot
  {
    float rv = bv, rx = bcx, ry = bcy, rz = bcz; int rg = bg;
#pragma unroll
    for (int m = 32; m >= 1; m >>= 1) {
      const float ov = __shfl_xor(rv, m, 64);
      const int   og = __shfl_xor(rg, m, 64);
      const float ox = __shfl_xor(rx, m, 64);
      const float oy = __shfl_xor(ry, m, 64);
      const float oz = __shfl_xor(rz, m, 64);
      if (ov > rv || (ov == rv && og < rg)) { rv = ov; rg = og; rx = ox; ry = oy; rz = oz; }
    }
    if (lane == 0) { s_v[0][wave] = rv; s_g[0][wave] = rg;
                     s_x[0][wave] = rx; s_y[0][wave] = ry; s_z[0][wave] = rz; }
  }
  __syncthreads();

  // ---- iterations 1..K-1 ----
  for (int j = 1; j < K_; ++j) {
    const int rp = (j - 1) & 1;
    const int wp = j & 1;

    // block finalize: butterfly over NWB_ slots (carry coords)
    float v = s_v[rp][lane & (NWB_ - 1)];
    int   g = s_g[rp][lane & (NWB_ - 1)];
    float fx = s_x[rp][lane & (NWB_ - 1)];
    float fy = s_y[rp][lane & (NWB_ - 1)];
    float fz = s_z[rp][lane & (NWB_ - 1)];
#pragma unroll
    for (int m = NWB_ / 2; m >= 1; m >>= 1) {
      const float ov = __shfl_xor(v, m, 64);
      const int   og = __shfl_xor(g, m, 64);
      const float ox = __shfl_xor(fx, m, 64);
      const float oy = __shfl_xor(fy, m, 64);
      const float oz = __shfl_xor(fz, m, 64);
      if (ov > v || (ov == v && og < g)) { v = ov; g = og; fx = ox; fy = oy; fz = oz; }
    }
    wcx = fx; wcy = fy; wcz = fz;   // winner coords, no memory load
    if (t == 0) {
      const uint64_t o = ((uint64_t)b * K_ + j) * 3;
      out_x[o + 0] = bfr(wcx); out_x[o + 1] = bfr(wcy); out_x[o + 2] = bfr(wcz);
    }

    // conservative chunk lower bound; skip update if provably unchanged
    const float dxm = fmaxf(fmaxf(bxl - wcx, wcx - bxh), 0.0f);
    const float dym = fmaxf(fmaxf(byl - wcy, wcy - byh), 0.0f);
    const float dzm = fmaxf(fmaxf(bzl - wcz, wcz - bzh), 0.0f);
    const float lb  = (dxm * dxm + dym * dym + dzm * dzm) * 0.999f;

    if (lb < bv) {
      bv = -1e38f; bg = 0x7fffffff;
#define UPDP(i) { const float d_ = dist_v1(px##i, py##i, pz##i, wcx, wcy, wcz); \
                  m##i = fminf(m##i, d_); TRKC(m##i, od##i, px##i, py##i, pz##i) }
      PTS_LIST(UPDP)
#undef UPDP
    }

    // wave reduce cached 5-tuple -> LDS slot (parity wp)
    float rv = bv, rx = bcx, ry = bcy, rz = bcz; int rg = bg;
#pragma unroll
    for (int m = 32; m >= 1; m >>= 1) {
      const float ov = __shfl_xor(rv, m, 64);
      const int   og = __shfl_xor(rg, m, 64);
      const float ox = __shfl_xor(rx, m, 64);
      const float oy = __shfl_xor(ry, m, 64);
      const float oz = __shfl_xor(rz, m, 64);
      if (ov > rv || (ov == rv && og < rg)) { rv = ov; rg = og; rx = ox; ry = oy; rz = oz; }
    }
    if (lane == 0) { s_v[wp][wave] = rv; s_g[wp][wave] = rg;
                     s_x[wp][wave] = rx; s_y[wp][wave] = ry; s_z[wp][wave] = rz; }
    __syncthreads();
  }
}

// ---------------- Fallback (R11, proven 8.0 ms): no ws needed ----------------
#define FTH_ 512
#define FNW_ (FTH_ / 64)
__global__ __attribute__((amdgpu_flat_work_group_size(FTH_, FTH_),
                          amdgpu_waves_per_eu(1, 2)))
void fps_fallback_kernel(const float* __restrict__ x, float* __restrict__ out)
{
#pragma clang fp contract(off)
  const int b = blockIdx.x, t = threadIdx.x, lane = t & 63, wave = t >> 6;
  __shared__ float s_v[2][FNW_];
  __shared__ int   s_g[2][FNW_];
  const float* xb  = x + (size_t)b * (N_ * 3);
  float* out_x     = out;
  float* out_batch = out + (size_t)B_ * K_ * 3;
  { const float bb = (float)b; for (int i = t; i < K_; i += FTH_) out_batch[b * K_ + i] = bb; }
#define DECLP(i) float px##i, py##i, pz##i, m##i;
  PTS_LIST(DECLP)
#undef DECLP
#define LOADP(i) { const float* p_ = xb + 3 * ((i) * FTH_ + t); \
                   px##i = p_[0]; py##i = p_[1]; pz##i = p_[2]; m##i = __builtin_inff(); }
  PTS_LIST(LOADP)
#undef LOADP
#define UPD(i) { const float d_ = dist_v1(px##i, py##i, pz##i, cx, cy, cz);     \
                 m##i = fminf(m##i, d_);                                        \
                 if (m##i > bv) { bv = m##i; bs = (i); } }
  float cx = xb[0], cy = xb[1], cz = xb[2];
  if (t == 0) {
    const uint64_t o = ((uint64_t)b * K_) * 3;
    out_x[o + 0] = bfr(cx); out_x[o + 1] = bfr(cy); out_x[o + 2] = bfr(cz);
  }
  float bv = -1.0f; int bs = 0;
  PTS_LIST(UPD)
  int bg = bs * FTH_ + t;
#pragma unroll
  for (int m = 32; m >= 1; m >>= 1) {
    const float ov = __shfl_xor(bv, m, 64);
    const int   og = __shfl_xor(bg, m, 64);
    if (ov > bv || (ov == bv && og < bg)) { bv = ov; bg = og; }
  }
  if (lane == 0) { s_v[0][wave] = bv; s_g[0][wave] = bg; }
  __syncthreads();
  for (int j = 1; j < K_; ++j) {
    const int rp = (j - 1) & 1, wp = j & 1;
    float v = s_v[rp][0]; int g = s_g[rp][0];
#pragma unroll
    for (int w = 1; w < FNW_; ++w) {
      const float ov = s_v[rp][w]; const int og = s_g[rp][w];
      if (ov > v || (ov == v && og < g)) { v = ov; g = og; }
    }
    const int gu = __builtin_amdgcn_readfirstlane(g);
    cx = xb[3 * gu + 0]; cy = xb[3 * gu + 1]; cz = xb[3 * gu + 2];
    if (t == 0) {
      const uint64_t o = ((uint64_t)b * K_ + j) * 3;
      out_x[o + 0] = bfr(cx); out_x[o + 1] = bfr(cy); out_x[o + 2] = bfr(cz);
    }
    bv = -1.0f; bs = 0;
    PTS_LIST(UPD)
    bg = bs * FTH_ + t;
#pragma unroll
    for (int m = 32; m >= 1; m >>= 1) {
      const float ov = __shfl_xor(bv, m, 64);
      const int   og = __shfl_xor(bg, m, 64);
      if (ov > bv || (ov == bv && og < bg)) { bv = ov; bg = og; }
    }
    if (lane == 0) { s_v[wp][wave] = bv; s_g[wp][wave] = bg; }
    __syncthreads();
  }
#undef UPD
}

extern "C" void kernel_launch(void* const* d_in, const int* in_sizes, int n_in,
                              void* d_out, int out_size, void* d_ws, size_t ws_size,
                              hipStream_t stream) {
  const float* x = (const float*)d_in[0];
  float* out     = (float*)d_out;
  (void)in_sizes; (void)n_in; (void)out_size;
  if (ws_size >= WS_NEED) {
    float* ws = (float*)d_ws;
    hipLaunchKernelGGL(fps_sort_kernel, dim3(B_), dim3(TA_), 0, stream, x, ws);
    hipLaunchKernelGGL(fps_main_kernel, dim3(B_), dim3(TB_), 0, stream, x, ws, out);
  } else {
    hipLaunchKernelGGL(fps_fallback_kernel, dim3(B_), dim3(FTH_), 0, stream, x, out);
  }
}

// Round 15
// 12880.553 us; speedup vs baseline: 1.4547x; 1.1219x over previous
//
#include <hip/hip_runtime.h>
#include <cstdint>

// Reference semantics (validated R8, absmax=0.0 — DO NOT change arithmetic):
//  - selection on RAW f32 coords, distance = fma(dz,dz, fma(dx,dx, dy*dy)),
//    dx/dy/dz plain f32 subs; min/argmax exact over (value, orig-index),
//    first-index tie-break (lex (max v, min g) — commutative/associative);
//  - output coords bf16-RNE-rounded, batch = float b.
//
// R15 = sorted 16-pt chunks (fits 128-reg cap: ~115 regs, no scratch)
//       + WAVE-uniform ballot skip (skipped wave: no update, no wave reduce,
//         just re-posts its cached reduce tuple to the parity slot)
//       + winner coords carried through the 16-slot finalize butterfly
//         (no dependent coord load on the serial chain).
// Skip proof: lane skip cond lb >= bv = max_i m_i, lb = bboxDist^2 * 0.999;
// computed d >= trueDist^2*(1-3eps) >= bboxDist^2*(1-3eps) > lb >= m_i
// (margin 1e-3 >> 4e-7) => fminf no-op and recompute would be bitwise
// identical => cached per-lane (bv,bg,coords) and per-wave reduce tuple
// remain exact.
#pragma clang fp contract(off)

#define B_ 16
#define N_ 16384
#define K_ 4096

#define TA_ 1024
#define PA_ (N_ / TA_)
#define NCELL_ 512              // 8^3 Morton cells

#define TB_ 1024
#define CH_ 16                  // points per chunk = per thread
#define NWB_ (TB_ / 64)         // 16 waves

// ws layout per cloud (4-byte units): xs, ys, zs, id, bbox[TB_*6]
#define WS_XS 0
#define WS_YS N_
#define WS_ZS (2 * N_)
#define WS_ID (3 * N_)
#define WS_BB (4 * N_)
#define WS_CLOUD (4 * N_ + TB_ * 6)
#define WS_NEED ((size_t)B_ * WS_CLOUD * 4)

#define PTS16_LIST(X) \
  X(0) X(1) X(2) X(3) X(4) X(5) X(6) X(7) \
  X(8) X(9) X(10) X(11) X(12) X(13) X(14) X(15)

__device__ __forceinline__ float bfr(float f) {
  union { float f; uint32_t i; } c; c.f = f;
  c.i = (c.i + 0x7FFFu + ((c.i >> 16) & 1u)) & 0xFFFF0000u;
  return c.f;
}

__device__ __forceinline__ float dist_v1(float px, float py, float pz,
                                         float cx, float cy, float cz) {
  const float dx = px - cx;
  const float dy = py - cy;
  const float dz = pz - cz;
  return __builtin_fmaf(dz, dz, __builtin_fmaf(dx, dx, dy * dy));
}

__device__ __forceinline__ int cell1(float v) {
  int k = (int)(v + 4.0f);
  return k < 0 ? 0 : (k > 7 ? 7 : k);
}
__device__ __forceinline__ int expand3(int b) {
  return (b & 1) | ((b & 2) << 2) | ((b & 4) << 4);
}
__device__ __forceinline__ int mkey(float vx, float vy, float vz) {
  return (expand3(cell1(vx)) << 2) | (expand3(cell1(vy)) << 1) | expand3(cell1(vz));
}

// ---------------- Phase A: Morton counting sort + chunk bboxes ----------------
__global__ __launch_bounds__(TA_) void fps_sort_kernel(
    const float* __restrict__ x, float* __restrict__ ws)
{
  const int b = blockIdx.x, t = threadIdx.x;
  __shared__ int hist[NCELL_];
  __shared__ int scan[NCELL_];
  const float* xb = x + (size_t)b * (N_ * 3);
  float* wsc = ws + (size_t)b * WS_CLOUD;
  int* oid = (int*)(wsc + WS_ID);

  for (int i = t; i < NCELL_; i += TA_) hist[i] = 0;
  __syncthreads();
  for (int s = 0; s < PA_; ++s) {
    const int g = s * TA_ + t;
    atomicAdd(&hist[mkey(xb[3 * g], xb[3 * g + 1], xb[3 * g + 2])], 1);
  }
  __syncthreads();
  if (t < NCELL_) scan[t] = hist[t];
  __syncthreads();
  for (int d = 1; d < NCELL_; d <<= 1) {
    int v = 0;
    if (t < NCELL_) { v = scan[t]; if (t >= d) v += scan[t - d]; }
    __syncthreads();
    if (t < NCELL_) scan[t] = v;
    __syncthreads();
  }
  if (t < NCELL_) hist[t] = (t == 0) ? 0 : scan[t - 1];
  __syncthreads();
  for (int s = 0; s < PA_; ++s) {
    const int g = s * TA_ + t;
    const float vx = xb[3 * g], vy = xb[3 * g + 1], vz = xb[3 * g + 2];
    const int pos = atomicAdd(&hist[mkey(vx, vy, vz)], 1);
    wsc[WS_XS + pos] = vx;
    wsc[WS_YS + pos] = vy;
    wsc[WS_ZS + pos] = vz;
    oid[pos] = g;
  }
  __threadfence();
  __syncthreads();
  {
    const int base = t * CH_;
    float xl = 1e30f, xh = -1e30f, yl = 1e30f, yh = -1e30f, zl = 1e30f, zh = -1e30f;
    for (int i = 0; i < CH_; ++i) {
      const float vx = wsc[WS_XS + base + i];
      const float vy = wsc[WS_YS + base + i];
      const float vz = wsc[WS_ZS + base + i];
      xl = fminf(xl, vx); xh = fmaxf(xh, vx);
      yl = fminf(yl, vy); yh = fmaxf(yh, vy);
      zl = fminf(zl, vz); zh = fmaxf(zh, vz);
    }
    float* bb = wsc + WS_BB + t * 6;
    bb[0] = xl; bb[1] = xh; bb[2] = yl; bb[3] = yh; bb[4] = zl; bb[5] = zh;
  }
}

// ---------------- Phase B: ballot-skip FPS, register-resident chunks ----------
__global__ __attribute__((amdgpu_flat_work_group_size(TB_, TB_)))
void fps_main_kernel(const float* __restrict__ x, const float* __restrict__ ws,
                     float* __restrict__ out)
{
#pragma clang fp contract(off)
  const int b = blockIdx.x, t = threadIdx.x, lane = t & 63, wave = t >> 6;
  __shared__ float s_v[2][NWB_], s_x[2][NWB_], s_y[2][NWB_], s_z[2][NWB_];
  __shared__ int   s_g[2][NWB_];

  const float* xb  = x + (size_t)b * (N_ * 3);
  const float* wsc = ws + (size_t)b * WS_CLOUD;
  const float* xs  = wsc + WS_XS;
  const float* ysv = wsc + WS_YS;
  const float* zsv = wsc + WS_ZS;
  const int*   oid = (const int*)(wsc + WS_ID);

  float* out_x = out;
  float* out_b = out + (size_t)B_ * K_ * 3;
  { const float bb = (float)b; for (int i = t; i < K_; i += TB_) out_b[b * K_ + i] = bb; }

  const float* bbp = wsc + WS_BB + t * 6;
  const float bxl = bbp[0], bxh = bbp[1], byl = bbp[2], byh = bbp[3], bzl = bbp[4], bzh = bbp[5];
  const int base = t * CH_;

  // named per-point scalars (16 pts: coords + mind + orig index)
#define DECLP(i) float px##i, py##i, pz##i, m##i; int od##i;
  PTS16_LIST(DECLP)
#undef DECLP
#define LOADP(i) { px##i = xs[base + (i)]; py##i = ysv[base + (i)]; \
                   pz##i = zsv[base + (i)]; od##i = oid[base + (i)]; }
  PTS16_LIST(LOADP)
#undef LOADP

  // per-lane cached chunk best (value, orig idx, that point's coords)
  float bv = -1e38f, bcx, bcy, bcz; int bg = 0x7fffffff;
  // per-wave cached reduce tuple (uniform across lanes after reduce)
  float cv, ccx, ccy, ccz; int cg;

#define TRKC(mv, ov, qx, qy, qz) \
  if ((mv) > bv || ((mv) == bv && (ov) < bg)) { \
    bv = (mv); bg = (ov); bcx = (qx); bcy = (qy); bcz = (qz); }

  // ---- iteration 0: seed = original point 0 ----
  float wcx = xb[0], wcy = xb[1], wcz = xb[2];
  if (t == 0) {
    const uint64_t o = ((uint64_t)b * K_) * 3;
    out_x[o + 0] = bfr(wcx); out_x[o + 1] = bfr(wcy); out_x[o + 2] = bfr(wcz);
  }

#define INITP(i) { const float d_ = dist_v1(px##i, py##i, pz##i, wcx, wcy, wcz); \
                   m##i = d_; TRKC(m##i, od##i, px##i, py##i, pz##i) }
  PTS16_LIST(INITP)
#undef INITP
  // 64-lane 5-tuple reduce -> wave cache
  {
    cv = bv; cg = bg; ccx = bcx; ccy = bcy; ccz = bcz;
#pragma unroll
    for (int m = 32; m >= 1; m >>= 1) {
      const float ov = __shfl_xor(cv, m, 64);
      const int   og = __shfl_xor(cg, m, 64);
      const float ox = __shfl_xor(ccx, m, 64);
      const float oy = __shfl_xor(ccy, m, 64);
      const float oz = __shfl_xor(ccz, m, 64);
      if (ov > cv || (ov == cv && og < cg)) { cv = ov; cg = og; ccx = ox; ccy = oy; ccz = oz; }
    }
    if (lane == 0) { s_v[0][wave] = cv; s_g[0][wave] = cg;
                     s_x[0][wave] = ccx; s_y[0][wave] = ccy; s_z[0][wave] = ccz; }
  }
  __syncthreads();

  // ---- iterations 1..K-1 ----
  for (int j = 1; j < K_; ++j) {
    const int rp = (j - 1) & 1;
    const int wp = j & 1;

    // finalize: butterfly allreduce over the 16 per-wave slots (coords carried)
    float v  = s_v[rp][lane & 15];
    int   g  = s_g[rp][lane & 15];
    float fx = s_x[rp][lane & 15];
    float fy = s_y[rp][lane & 15];
    float fz = s_z[rp][lane & 15];
#pragma unroll
    for (int m = 8; m >= 1; m >>= 1) {
      const float ov = __shfl_xor(v, m, 64);
      const int   og = __shfl_xor(g, m, 64);
      const float ox = __shfl_xor(fx, m, 64);
      const float oy = __shfl_xor(fy, m, 64);
      const float oz = __shfl_xor(fz, m, 64);
      if (ov > v || (ov == v && og < g)) { v = ov; g = og; fx = ox; fy = oy; fz = oz; }
    }
    wcx = fx; wcy = fy; wcz = fz;
    if (t == 0) {
      const uint64_t o = ((uint64_t)b * K_ + j) * 3;
      out_x[o + 0] = bfr(wcx); out_x[o + 1] = bfr(wcy); out_x[o + 2] = bfr(wcz);
    }

    // conservative chunk lower bound; wave-uniform skip via ballot
    const float dxm = fmaxf(fmaxf(bxl - wcx, wcx - bxh), 0.0f);
    const float dym = fmaxf(fmaxf(byl - wcy, wcy - byh), 0.0f);
    const float dzm = fmaxf(fmaxf(bzl - wcz, wcz - bzh), 0.0f);
    const float lb  = (dxm * dxm + dym * dym + dzm * dzm) * 0.999f;

    if (__ballot(lb < bv)) {
      // some chunk in this wave may change: recompute all lanes (bitwise
      // no-op for unaffected lanes), then redo the wave reduce.
      bv = -1e38f; bg = 0x7fffffff;
#define UPDP(i) { const float d_ = dist_v1(px##i, py##i, pz##i, wcx, wcy, wcz); \
                  m##i = fminf(m##i, d_); TRKC(m##i, od##i, px##i, py##i, pz##i) }
      PTS16_LIST(UPDP)
#undef UPDP
      cv = bv; cg = bg; ccx = bcx; ccy = bcy; ccz = bcz;
#pragma unroll
      for (int m = 32; m >= 1; m >>= 1) {
        const float ov = __shfl_xor(cv, m, 64);
        const int   og = __shfl_xor(cg, m, 64);
        const float ox = __shfl_xor(ccx, m, 64);
        const float oy = __shfl_xor(ccy, m, 64);
        const float oz = __shfl_xor(ccz, m, 64);
        if (ov > cv || (ov == cv && og < cg)) { cv = ov; cg = og; ccx = ox; ccy = oy; ccz = oz; }
      }
    }
    // every wave re-posts its (possibly cached) reduce tuple to parity slot
    if (lane == 0) { s_v[wp][wave] = cv; s_g[wp][wave] = cg;
                     s_x[wp][wave] = ccx; s_y[wp][wave] = ccy; s_z[wp][wave] = ccz; }
    __syncthreads();
  }
}

// ---------------- Fallback (R11, proven 8.0 ms): no ws needed ----------------
#define FTH_ 512
#define FNW_ (FTH_ / 64)
#define PTS32_LIST(X) \
  X(0) X(1) X(2) X(3) X(4) X(5) X(6) X(7) \
  X(8) X(9) X(10) X(11) X(12) X(13) X(14) X(15) \
  X(16) X(17) X(18) X(19) X(20) X(21) X(22) X(23) \
  X(24) X(25) X(26) X(27) X(28) X(29) X(30) X(31)

__global__ __attribute__((amdgpu_flat_work_group_size(FTH_, FTH_),
                          amdgpu_waves_per_eu(1, 2)))
void fps_fallback_kernel(const float* __restrict__ x, float* __restrict__ out)
{
#pragma clang fp contract(off)
  const int b = blockIdx.x, t = threadIdx.x, lane = t & 63, wave = t >> 6;
  __shared__ float s_v[2][FNW_];
  __shared__ int   s_g[2][FNW_];
  const float* xb  = x + (size_t)b * (N_ * 3);
  float* out_x     = out;
  float* out_batch = out + (size_t)B_ * K_ * 3;
  { const float bb = (float)b; for (int i = t; i < K_; i += FTH_) out_batch[b * K_ + i] = bb; }
#define DECLP(i) float px##i, py##i, pz##i, m##i;
  PTS32_LIST(DECLP)
#undef DECLP
#define LOADP(i) { const float* p_ = xb + 3 * ((i) * FTH_ + t); \
                   px##i = p_[0]; py##i = p_[1]; pz##i = p_[2]; m##i = __builtin_inff(); }
  PTS32_LIST(LOADP)
#undef LOADP
#define UPD(i) { const float d_ = dist_v1(px##i, py##i, pz##i, cx, cy, cz);     \
                 m##i = fminf(m##i, d_);                                        \
                 if (m##i > bv) { bv = m##i; bs = (i); } }
  float cx = xb[0], cy = xb[1], cz = xb[2];
  if (t == 0) {
    const uint64_t o = ((uint64_t)b * K_) * 3;
    out_x[o + 0] = bfr(cx); out_x[o + 1] = bfr(cy); out_x[o + 2] = bfr(cz);
  }
  float bv = -1.0f; int bs = 0;
  PTS32_LIST(UPD)
  int bg = bs * FTH_ + t;
#pragma unroll
  for (int m = 32; m >= 1; m >>= 1) {
    const float ov = __shfl_xor(bv, m, 64);
    const int   og = __shfl_xor(bg, m, 64);
    if (ov > bv || (ov == bv && og < bg)) { bv = ov; bg = og; }
  }
  if (lane == 0) { s_v[0][wave] = bv; s_g[0][wave] = bg; }
  __syncthreads();
  for (int j = 1; j < K_; ++j) {
    const int rp = (j - 1) & 1, wp = j & 1;
    float v = s_v[rp][0]; int g = s_g[rp][0];
#pragma unroll
    for (int w = 1; w < FNW_; ++w) {
      const float ov = s_v[rp][w]; const int og = s_g[rp][w];
      if (ov > v || (ov == v && og < g)) { v = ov; g = og; }
    }
    const int gu = __builtin_amdgcn_readfirstlane(g);
    cx = xb[3 * gu + 0]; cy = xb[3 * gu + 1]; cz = xb[3 * gu + 2];
    if (t == 0) {
      const uint64_t o = ((uint64_t)b * K_ + j) * 3;
      out_x[o + 0] = bfr(cx); out_x[o + 1] = bfr(cy); out_x[o + 2] = bfr(cz);
    }
    bv = -1.0f; bs = 0;
    PTS32_LIST(UPD)
    bg = bs * FTH_ + t;
#pragma unroll
    for (int m = 32; m >= 1; m >>= 1) {
      const float ov = __shfl_xor(bv, m, 64);
      const int   og = __shfl_xor(bg, m, 64);
      if (ov > bv || (ov == bv && og < bg)) { bv = ov; bg = og; }
    }
    if (lane == 0) { s_v[wp][wave] = bv; s_g[wp][wave] = bg; }
    __syncthreads();
  }
#undef UPD
}

extern "C" void kernel_launch(void* const* d_in, const int* in_sizes, int n_in,
                              void* d_out, int out_size, void* d_ws, size_t ws_size,
                              hipStream_t stream) {
  const float* x = (const float*)d_in[0];
  float* out     = (float*)d_out;
  (void)in_sizes; (void)n_in; (void)out_size;
  if (ws_size >= WS_NEED) {
    float* ws = (float*)d_ws;
    hipLaunchKernelGGL(fps_sort_kernel, dim3(B_), dim3(TA_), 0, stream, x, ws);
    hipLaunchKernelGGL(fps_main_kernel, dim3(B_), dim3(TB_), 0, stream, x, ws, out);
  } else {
    hipLaunchKernelGGL(fps_fallback_kernel, dim3(B_), dim3(FTH_), 0, stream, x, out);
  }
}

// Round 16
// 12346.523 us; speedup vs baseline: 1.5176x; 1.0433x over previous
//
#include <hip/hip_runtime.h>
#include <cstdint>

// Reference semantics (validated R8, absmax=0.0 — DO NOT change arithmetic):
//  - selection on RAW f32 coords, distance = fma(dz,dz, fma(dx,dx, dy*dy)),
//    dx/dy/dz plain f32 subs; min/argmax exact over (value, orig-index),
//    first-index tie-break (lex (max v, min od) — commutative/associative);
//  - output coords bf16-RNE-rounded, batch = float b.
//
// R16 = R15 ballot-skip + STATE DIET so the 1024-thr allocator budget is not
// exceeded (R14/R15 regressed on scratch: WRITE_SIZE 1920/3328 KB):
//  - od -> LDS u16 (32 KB, transposed, read only by updating waves);
//  - coords+m+bbox+caches in regs (~95 need ~= R12's no-scratch envelope);
//  - skipped wave: no update, no reduce, lane0 re-posts cached 5-tuple.
// Skip proof: lane cond lb >= bv (lb = bboxDist^2*0.999): computed
// d >= trueDist^2*(1-3eps) >= bboxDist^2*(1-3eps) > lb >= bv >= m_i, margin
// 1e-3 >> 4e-7 => fminf no-op, recompute bitwise identical => caches exact.
#pragma clang fp contract(off)

#define B_ 16
#define N_ 16384
#define K_ 4096

#define TA_ 1024
#define PA_ (N_ / TA_)
#define NCELL_ 512              // 8^3 Morton cells

#define TB_ 1024
#define CH_ 16                  // points per chunk = per thread
#define NWB_ (TB_ / 64)         // 16 waves

// ws layout per cloud (4-byte units): xs, ys, zs, od(int32), bbox[TB_*6]
#define WS_XS 0
#define WS_YS N_
#define WS_ZS (2 * N_)
#define WS_ID (3 * N_)
#define WS_BB (4 * N_)
#define WS_CLOUD (4 * N_ + TB_ * 6)
#define WS_NEED ((size_t)B_ * WS_CLOUD * 4)

#define PTS16_LIST(X) \
  X(0) X(1) X(2) X(3) X(4) X(5) X(6) X(7) \
  X(8) X(9) X(10) X(11) X(12) X(13) X(14) X(15)

__device__ __forceinline__ float bfr(float f) {
  union { float f; uint32_t i; } c; c.f = f;
  c.i = (c.i + 0x7FFFu + ((c.i >> 16) & 1u)) & 0xFFFF0000u;
  return c.f;
}

__device__ __forceinline__ float dist_v1(float px, float py, float pz,
                                         float cx, float cy, float cz) {
  const float dx = px - cx;
  const float dy = py - cy;
  const float dz = pz - cz;
  return __builtin_fmaf(dz, dz, __builtin_fmaf(dx, dx, dy * dy));
}

__device__ __forceinline__ int cell1(float v) {
  int k = (int)(v + 4.0f);
  return k < 0 ? 0 : (k > 7 ? 7 : k);
}
__device__ __forceinline__ int expand3(int b) {
  return (b & 1) | ((b & 2) << 2) | ((b & 4) << 4);
}
__device__ __forceinline__ int mkey(float vx, float vy, float vz) {
  return (expand3(cell1(vx)) << 2) | (expand3(cell1(vy)) << 1) | expand3(cell1(vz));
}

// ---------------- Phase A: Morton counting sort + chunk bboxes ----------------
__global__ __launch_bounds__(TA_) void fps_sort_kernel(
    const float* __restrict__ x, float* __restrict__ ws)
{
  const int b = blockIdx.x, t = threadIdx.x;
  __shared__ int hist[NCELL_];
  __shared__ int scan[NCELL_];
  const float* xb = x + (size_t)b * (N_ * 3);
  float* wsc = ws + (size_t)b * WS_CLOUD;
  int* oid = (int*)(wsc + WS_ID);

  for (int i = t; i < NCELL_; i += TA_) hist[i] = 0;
  __syncthreads();
  for (int s = 0; s < PA_; ++s) {
    const int g = s * TA_ + t;
    atomicAdd(&hist[mkey(xb[3 * g], xb[3 * g + 1], xb[3 * g + 2])], 1);
  }
  __syncthreads();
  if (t < NCELL_) scan[t] = hist[t];
  __syncthreads();
  for (int d = 1; d < NCELL_; d <<= 1) {
    int v = 0;
    if (t < NCELL_) { v = scan[t]; if (t >= d) v += scan[t - d]; }
    __syncthreads();
    if (t < NCELL_) scan[t] = v;
    __syncthreads();
  }
  if (t < NCELL_) hist[t] = (t == 0) ? 0 : scan[t - 1];
  __syncthreads();
  for (int s = 0; s < PA_; ++s) {
    const int g = s * TA_ + t;
    const float vx = xb[3 * g], vy = xb[3 * g + 1], vz = xb[3 * g + 2];
    const int pos = atomicAdd(&hist[mkey(vx, vy, vz)], 1);
    wsc[WS_XS + pos] = vx;
    wsc[WS_YS + pos] = vy;
    wsc[WS_ZS + pos] = vz;
    oid[pos] = g;
  }
  __threadfence();
  __syncthreads();
  {
    const int base = t * CH_;
    float xl = 1e30f, xh = -1e30f, yl = 1e30f, yh = -1e30f, zl = 1e30f, zh = -1e30f;
    for (int i = 0; i < CH_; ++i) {
      const float vx = wsc[WS_XS + base + i];
      const float vy = wsc[WS_YS + base + i];
      const float vz = wsc[WS_ZS + base + i];
      xl = fminf(xl, vx); xh = fmaxf(xh, vx);
      yl = fminf(yl, vy); yh = fmaxf(yh, vy);
      zl = fminf(zl, vz); zh = fmaxf(zh, vz);
    }
    float* bb = wsc + WS_BB + t * 6;
    bb[0] = xl; bb[1] = xh; bb[2] = yl; bb[3] = yh; bb[4] = zl; bb[5] = zh;
  }
}

// ---------------- Phase B: ballot-skip FPS, dieted register state ------------
__global__ __attribute__((amdgpu_flat_work_group_size(TB_, TB_),
                          amdgpu_waves_per_eu(4, 4)))
void fps_main_kernel(const float* __restrict__ x, const float* __restrict__ ws,
                     float* __restrict__ out)
{
#pragma clang fp contract(off)
  const int b = blockIdx.x, t = threadIdx.x, lane = t & 63, wave = t >> 6;
  __shared__ float s_v[2][NWB_], s_x[2][NWB_], s_y[2][NWB_], s_z[2][NWB_];
  __shared__ int   s_g[2][NWB_];
  __shared__ unsigned short od16[N_];   // 32 KB, transposed [i*TB_ + t]

  const float* xb  = x + (size_t)b * (N_ * 3);
  const float* wsc = ws + (size_t)b * WS_CLOUD;
  const float* xs  = wsc + WS_XS;
  const float* ysv = wsc + WS_YS;
  const float* zsv = wsc + WS_ZS;
  const int*   oid = (const int*)(wsc + WS_ID);

  float* out_x = out;
  float* out_b = out + (size_t)B_ * K_ * 3;
  { const float bb = (float)b; for (int i = t; i < K_; i += TB_) out_b[b * K_ + i] = bb; }

  const float* bbp = wsc + WS_BB + t * 6;
  const float bxl = bbp[0], bxh = bbp[1], byl = bbp[2], byh = bbp[3], bzl = bbp[4], bzh = bbp[5];
  const int base = t * CH_;

  // stage orig indices into LDS as u16 (transposed: od16[i*TB_ + t])
  for (int i = 0; i < CH_; ++i) od16[i * TB_ + t] = (unsigned short)oid[base + i];

  // named per-point scalars (16 pts: coords + mind)
#define DECLP(i) float px##i, py##i, pz##i, m##i;
  PTS16_LIST(DECLP)
#undef DECLP
#define LOADP(i) { px##i = xs[base + (i)]; py##i = ysv[base + (i)]; \
                   pz##i = zsv[base + (i)]; }
  PTS16_LIST(LOADP)
#undef LOADP
  __syncthreads();   // od16 staged

  // per-lane cached chunk best; per-wave cached reduce tuple
  float bv = -1e38f, bcx = 0.f, bcy = 0.f, bcz = 0.f; int bg = 0x7fffffff;
  float cv, ccx, ccy, ccz; int cg;

#define TRKC(mv, ov, qx, qy, qz) \
  if ((mv) > bv || ((mv) == bv && (ov) < bg)) { \
    bv = (mv); bg = (ov); bcx = (qx); bcy = (qy); bcz = (qz); }

  // ---- iteration 0: seed = original point 0 ----
  float wcx = xb[0], wcy = xb[1], wcz = xb[2];
  if (t == 0) {
    const uint64_t o = ((uint64_t)b * K_) * 3;
    out_x[o + 0] = bfr(wcx); out_x[o + 1] = bfr(wcy); out_x[o + 2] = bfr(wcz);
  }

#define INITP(i) { const float d_ = dist_v1(px##i, py##i, pz##i, wcx, wcy, wcz); \
                   m##i = d_; const int od_ = od16[(i) * TB_ + t];               \
                   TRKC(m##i, od_, px##i, py##i, pz##i) }
  PTS16_LIST(INITP)
#undef INITP
  // wave allreduce (bv,bg) + winner-lane coord broadcast -> wave cache
  {
    cv = bv; cg = bg;
#pragma unroll
    for (int m = 32; m >= 1; m >>= 1) {
      const float ov = __shfl_xor(cv, m, 64);
      const int   og = __shfl_xor(cg, m, 64);
      if (ov > cv || (ov == cv && og < cg)) { cv = ov; cg = og; }
    }
    const unsigned long long wm = __ballot(bv == cv && bg == cg);
    const int wl = __ffsll(wm) - 1;
    ccx = __shfl(bcx, wl, 64); ccy = __shfl(bcy, wl, 64); ccz = __shfl(bcz, wl, 64);
    if (lane == 0) { s_v[0][wave] = cv; s_g[0][wave] = cg;
                     s_x[0][wave] = ccx; s_y[0][wave] = ccy; s_z[0][wave] = ccz; }
  }
  __syncthreads();

  // ---- iterations 1..K-1 ----
  for (int j = 1; j < K_; ++j) {
    const int rp = (j - 1) & 1;
    const int wp = j & 1;

    // finalize: butterfly allreduce over the 16 per-wave slots (coords carried)
    float v  = s_v[rp][lane & 15];
    int   g  = s_g[rp][lane & 15];
    float fx = s_x[rp][lane & 15];
    float fy = s_y[rp][lane & 15];
    float fz = s_z[rp][lane & 15];
#pragma unroll
    for (int m = 8; m >= 1; m >>= 1) {
      const float ov = __shfl_xor(v, m, 64);
      const int   og = __shfl_xor(g, m, 64);
      const float ox = __shfl_xor(fx, m, 64);
      const float oy = __shfl_xor(fy, m, 64);
      const float oz = __shfl_xor(fz, m, 64);
      if (ov > v || (ov == v && og < g)) { v = ov; g = og; fx = ox; fy = oy; fz = oz; }
    }
    wcx = fx; wcy = fy; wcz = fz;
    if (t == 0) {
      const uint64_t o = ((uint64_t)b * K_ + j) * 3;
      out_x[o + 0] = bfr(wcx); out_x[o + 1] = bfr(wcy); out_x[o + 2] = bfr(wcz);
    }

    // conservative chunk lower bound; wave-uniform skip via ballot
    const float dxm = fmaxf(fmaxf(bxl - wcx, wcx - bxh), 0.0f);
    const float dym = fmaxf(fmaxf(byl - wcy, wcy - byh), 0.0f);
    const float dzm = fmaxf(fmaxf(bzl - wcz, wcz - bzh), 0.0f);
    const float lb  = (dxm * dxm + dym * dym + dzm * dzm) * 0.999f;

    if (__ballot(lb < bv)) {
      bv = -1e38f; bg = 0x7fffffff;
#define UPDP(i) { const float d_ = dist_v1(px##i, py##i, pz##i, wcx, wcy, wcz); \
                  m##i = fminf(m##i, d_); const int od_ = od16[(i) * TB_ + t];  \
                  TRKC(m##i, od_, px##i, py##i, pz##i) }
      PTS16_LIST(UPDP)
#undef UPDP
      cv = bv; cg = bg;
#pragma unroll
      for (int m = 32; m >= 1; m >>= 1) {
        const float ov = __shfl_xor(cv, m, 64);
        const int   og = __shfl_xor(cg, m, 64);
        if (ov > cv || (ov == cv && og < cg)) { cv = ov; cg = og; }
      }
      const unsigned long long wm = __ballot(bv == cv && bg == cg);
      const int wl = __ffsll(wm) - 1;
      ccx = __shfl(bcx, wl, 64); ccy = __shfl(bcy, wl, 64); ccz = __shfl(bcz, wl, 64);
    }
    // every wave posts its (possibly cached) tuple to the parity slot
    if (lane == 0) { s_v[wp][wave] = cv; s_g[wp][wave] = cg;
                     s_x[wp][wave] = ccx; s_y[wp][wave] = ccy; s_z[wp][wave] = ccz; }
    __syncthreads();
  }
}

// ---------------- Fallback (R11, proven 8.0 ms): no ws needed ----------------
#define FTH_ 512
#define FNW_ (FTH_ / 64)
#define PTS32_LIST(X) \
  X(0) X(1) X(2) X(3) X(4) X(5) X(6) X(7) \
  X(8) X(9) X(10) X(11) X(12) X(13) X(14) X(15) \
  X(16) X(17) X(18) X(19) X(20) X(21) X(22) X(23) \
  X(24) X(25) X(26) X(27) X(28) X(29) X(30) X(31)

__global__ __attribute__((amdgpu_flat_work_group_size(FTH_, FTH_),
                          amdgpu_waves_per_eu(1, 2)))
void fps_fallback_kernel(const float* __restrict__ x, float* __restrict__ out)
{
#pragma clang fp contract(off)
  const int b = blockIdx.x, t = threadIdx.x, lane = t & 63, wave = t >> 6;
  __shared__ float s_v[2][FNW_];
  __shared__ int   s_g[2][FNW_];
  const float* xb  = x + (size_t)b * (N_ * 3);
  float* out_x     = out;
  float* out_batch = out + (size_t)B_ * K_ * 3;
  { const float bb = (float)b; for (int i = t; i < K_; i += FTH_) out_batch[b * K_ + i] = bb; }
#define DECLP(i) float px##i, py##i, pz##i, m##i;
  PTS32_LIST(DECLP)
#undef DECLP
#define LOADP(i) { const float* p_ = xb + 3 * ((i) * FTH_ + t); \
                   px##i = p_[0]; py##i = p_[1]; pz##i = p_[2]; m##i = __builtin_inff(); }
  PTS32_LIST(LOADP)
#undef LOADP
#define UPD(i) { const float d_ = dist_v1(px##i, py##i, pz##i, cx, cy, cz);     \
                 m##i = fminf(m##i, d_);                                        \
                 if (m##i > bv) { bv = m##i; bs = (i); } }
  float cx = xb[0], cy = xb[1], cz = xb[2];
  if (t == 0) {
    const uint64_t o = ((uint64_t)b * K_) * 3;
    out_x[o + 0] = bfr(cx); out_x[o + 1] = bfr(cy); out_x[o + 2] = bfr(cz);
  }
  float bv = -1.0f; int bs = 0;
  PTS32_LIST(UPD)
  int bg = bs * FTH_ + t;
#pragma unroll
  for (int m = 32; m >= 1; m >>= 1) {
    const float ov = __shfl_xor(bv, m, 64);
    const int   og = __shfl_xor(bg, m, 64);
    if (ov > bv || (ov == bv && og < bg)) { bv = ov; bg = og; }
  }
  if (lane == 0) { s_v[0][wave] = bv; s_g[0][wave] = bg; }
  __syncthreads();
  for (int j = 1; j < K_; ++j) {
    const int rp = (j - 1) & 1, wp = j & 1;
    float v = s_v[rp][0]; int g = s_g[rp][0];
#pragma unroll
    for (int w = 1; w < FNW_; ++w) {
      const float ov = s_v[rp][w]; const int og = s_g[rp][w];
      if (ov > v || (ov == v && og < g)) { v = ov; g = og; }
    }
    const int gu = __builtin_amdgcn_readfirstlane(g);
    cx = xb[3 * gu + 0]; cy = xb[3 * gu + 1]; cz = xb[3 * gu + 2];
    if (t == 0) {
      const uint64_t o = ((uint64_t)b * K_ + j) * 3;
      out_x[o + 0] = bfr(cx); out_x[o + 1] = bfr(cy); out_x[o + 2] = bfr(cz);
    }
    bv = -1.0f; bs = 0;
    PTS32_LIST(UPD)
    bg = bs * FTH_ + t;
#pragma unroll
    for (int m = 32; m >= 1; m >>= 1) {
      const float ov = __shfl_xor(bv, m, 64);
      const int   og = __shfl_xor(bg, m, 64);
      if (ov > bv || (ov == bv && og < bg)) { bv = ov; bg = og; }
    }
    if (lane == 0) { s_v[wp][wave] = bv; s_g[wp][wave] = bg; }
    __syncthreads();
  }
#undef UPD
}

extern "C" void kernel_launch(void* const* d_in, const int* in_sizes, int n_in,
                              void* d_out, int out_size, void* d_ws, size_t ws_size,
                              hipStream_t stream) {
  const float* x = (const float*)d_in[0];
  float* out     = (float*)d_out;
  (void)in_sizes; (void)n_in; (void)out_size;
  if (ws_size >= WS_NEED) {
    float* ws = (float*)d_ws;
    hipLaunchKernelGGL(fps_sort_kernel, dim3(B_), dim3(TA_), 0, stream, x, ws);
    hipLaunchKernelGGL(fps_main_kernel, dim3(B_), dim3(TB_), 0, stream, x, ws, out);
  } else {
    hipLaunchKernelGGL(fps_fallback_kernel, dim3(B_), dim3(FTH_), 0, stream, x, out);
  }
}